// Round 18
// baseline (2869.313 us; speedup 1.0000x reference)
//
#include <hip/hip_runtime.h>
#include <hip/hip_fp16.h>

#define TT 1024
#define BB 128
#define II 256
#define HH 256
#define NG 768   // 3*H

// Static scratch: x bf16, wih^T bf16, gi f16 (bias folded in).
__device__ __align__(16) unsigned short g_xbf[(size_t)TT * BB * II];   // 67 MB
__device__ __align__(16) unsigned short g_wihB[NG * II];               // 384 KB
__device__ __align__(16) _Float16       g_gi[(size_t)TT * BB * NG];    // 201 MB

typedef __attribute__((ext_vector_type(8))) short    bfrag;
typedef __attribute__((ext_vector_type(8))) _Float16 hfrag;
typedef __attribute__((ext_vector_type(4))) float    f32x4;

__device__ __forceinline__ unsigned short f2bf(float f) {
    unsigned u = __float_as_uint(f);
    return (unsigned short)((u + 0x7fffu + ((u >> 16) & 1u)) >> 16);   // RNE
}

// ---------------- phase 1a: x f32 -> bf16 ----------------
__global__ void cvt_x_kernel(const float* __restrict__ x) {
    const int n4 = TT * BB * II / 4;
    for (int i = blockIdx.x * blockDim.x + threadIdx.x; i < n4;
         i += gridDim.x * blockDim.x) {
        float4 v = reinterpret_cast<const float4*>(x)[i];
        ushort4 o;
        o.x = f2bf(v.x); o.y = f2bf(v.y); o.z = f2bf(v.z); o.w = f2bf(v.w);
        reinterpret_cast<ushort4*>(g_xbf)[i] = o;
    }
}

// ---------------- phase 1b: wihT [k][n] -> wihB [n][k] bf16 ----------------
__global__ void cvt_wih_kernel(const float* __restrict__ wihT) {
    const int n = blockIdx.x;
    const int k = threadIdx.x;
    g_wihB[n * II + k] = f2bf(wihT[k * NG + n]);
}

// ---------------- phase 2: gi = x @ wihT + bias (MFMA bf16, f16 out) ----------------
__global__ void __launch_bounds__(256) gi_gemm_kernel(const float* __restrict__ bias) {
    __shared__ unsigned short Ab[128 * 32];
    __shared__ unsigned short Bb[128 * 32];
    const int tid = threadIdx.x;
    const int mt = blockIdx.x / 6, nt = blockIdx.x % 6;
    const int m0 = mt * 128, n0 = nt * 128;
    const int l = tid & 63, w = tid >> 6;
    const int wr = w >> 1, wc = w & 1;
    const int srow = tid >> 2, scol = (tid & 3) * 8;

    f32x4 acc[4][4] = {};

    for (int ks = 0; ks < 8; ++ks) {
        const int k0 = ks * 32;
        __syncthreads();
        #pragma unroll
        for (int c = 0; c < 2; ++c) {
            const int row = c * 64 + srow;
            *reinterpret_cast<uint4*>(&Ab[row * 32 + scol]) =
                *reinterpret_cast<const uint4*>(&g_xbf[(size_t)(m0 + row) * II + k0 + scol]);
            *reinterpret_cast<uint4*>(&Bb[row * 32 + scol]) =
                *reinterpret_cast<const uint4*>(&g_wihB[(n0 + row) * II + k0 + scol]);
        }
        __syncthreads();
        bfrag af[4], bf[4];
        #pragma unroll
        for (int i = 0; i < 4; ++i) {
            af[i] = *reinterpret_cast<const bfrag*>(
                        &Ab[(wr * 64 + i * 16 + (l & 15)) * 32 + (l >> 4) * 8]);
            bf[i] = *reinterpret_cast<const bfrag*>(
                        &Bb[(wc * 64 + i * 16 + (l & 15)) * 32 + (l >> 4) * 8]);
        }
        #pragma unroll
        for (int mi = 0; mi < 4; ++mi)
            #pragma unroll
            for (int ni = 0; ni < 4; ++ni)
                acc[mi][ni] = __builtin_amdgcn_mfma_f32_16x16x32_bf16(
                                  af[mi], bf[ni], acc[mi][ni], 0, 0, 0);
    }
    #pragma unroll
    for (int mi = 0; mi < 4; ++mi) {
        const int grow = m0 + wr * 64 + mi * 16 + (l >> 4) * 4;
        #pragma unroll
        for (int ni = 0; ni < 4; ++ni) {
            const int gcol = n0 + wc * 64 + ni * 16 + (l & 15);
            const float bv = bias[gcol];
            #pragma unroll
            for (int q = 0; q < 4; ++q)
                g_gi[(size_t)(grow + q) * NG + gcol] = (_Float16)(acc[mi][ni][q] + bv);
        }
    }
}

// ---------------- phase 3: recurrence, AGPR-resident, 4 waves/SIMD ----------------
// Cycle model correction (r17 post-mortem): one 16x16x32 MFMA = ~16 cyc per
// SIMD (dense peak 1017 FLOP/cyc/SIMD), so the 96 resident frags per SIMD
// cost ~1536 cyc/step -- that is the hard floor of the all-resident design
// and was 54% of r17's 2840-cyc step. The other ~1300 cyc (AGPR copies, gi
// latency, epilogue, barrier) must be HIDDEN, which needs >2 waves/SIMD.
//
// This round: 128 WGs x 1024 threads (16 waves, 4/SIMD, 128 regs/lane).
// Wave w owns ONE column-set {16w (r), 256+16w (z), 512+16w (n)} -> 24
// B-frags = 96 words/lane pinned to AGPR; arch demand ~30 (3 accs, A frag,
// 3 gi, few addresses) fits the remaining 32. Per-wave step work: 8
// broadcast ds_read + 24 MFMA + one-column epilogue. Duplicated-A trick
// (all C rows equal) keeps it branchless; sel==0 lanes publish h.
#define MF(A, B, C) __builtin_amdgcn_mfma_f32_16x16x32_f16((A), (B), (C), 0, 0, 0)

#define LDB1(NAME, CB, KT)                                                  \
    hfrag NAME;                                                             \
    _Pragma("unroll")                                                       \
    for (int e = 0; e < 8; ++e)                                             \
        NAME[e] = (_Float16)whhT[(size_t)((KT) * 32 + g8 + e) * NG + (CB) + c]; \
    asm("" : "+a"(NAME));

#define DECL8(P, CB)                                                        \
    LDB1(P##_0, CB, 0) LDB1(P##_1, CB, 1) LDB1(P##_2, CB, 2)                \
    LDB1(P##_3, CB, 3) LDB1(P##_4, CB, 4) LDB1(P##_5, CB, 5)                \
    LDB1(P##_6, CB, 6) LDB1(P##_7, CB, 7)

#define KST(KT)                                                             \
    {                                                                       \
        const hfrag A = *reinterpret_cast<const hfrag*>(hl + (KT) * 32 + g8); \
        aR = MF(A, BR_##KT, aR);                                            \
        aZ = MF(A, BZ_##KT, aZ);                                            \
        aN = MF(A, BN_##KT, aN);                                            \
    }

__global__ void __launch_bounds__(1024, 1) gru_rec_kernel(
    const float* __restrict__ h0, const float* __restrict__ whhT,
    float* __restrict__ out)
{
    __shared__ __align__(16) _Float16 hbuf[2][HH];   // 1 KB ping-pong h (f16)

    const int t   = threadIdx.x;
    const int b   = blockIdx.x;
    const int w   = t >> 6;             // wave 0..15
    const int l   = t & 63;
    const int c   = l & 15;             // col within tile
    const int sel = l >> 4;             // 0..3 (duplicate groups)
    const int g8  = sel * 8;            // k-sub-chunk base
    const int cw  = w * 16;
    const int j   = cw + c;             // this wave's output column

    // --- 24 whh B-fragments (one column-set), ALL pinned to AGPR ---
    DECL8(BR, cw)
    DECL8(BZ, 256 + cw)
    DECL8(BN, 512 + cw)

    // --- init h ---
    float hp = h0[b * HH + j];
    if (sel == 0) hbuf[0][j] = (_Float16)hp;
    __syncthreads();

    for (int ts = 0; ts < TT; ++ts) {
        const _Float16* hl  = hbuf[ts & 1];
        _Float16*       hn_ = hbuf[(ts & 1) ^ 1];

        // gi for this step (bias pre-folded; hides under the MFMA block)
        const _Float16* gb = g_gi + ((size_t)ts * BB + b) * NG + j;
        const float gR = (float)gb[0];
        const float gZ = (float)gb[256];
        const float gN = (float)gb[512];

        f32x4 aR = {0.f,0.f,0.f,0.f};
        f32x4 aZ = {0.f,0.f,0.f,0.f};
        f32x4 aN = {0.f,0.f,0.f,0.f};
        KST(0) KST(1) KST(2) KST(3) KST(4) KST(5) KST(6) KST(7)

        // all C rows equal (duplicated A rows): acc[0] = gh[j] on every lane
        const float r  = 1.f / (1.f + __expf(-(aR[0] + gR)));
        const float z  = 1.f / (1.f + __expf(-(aZ[0] + gZ)));
        const float e  = __expf(2.f * (gN + r * aN[0]));   // tanh
        const float n  = 1.f - 2.f / (e + 1.f);
        const float hv = (1.f - z) * n + z * hp;

        hp = hv;
        if (sel == 0) {
            hn_[j] = (_Float16)hv;
            if (ts == TT - 1) out[b * HH + j] = hv;
        }
        __syncthreads();
    }
}

extern "C" void kernel_launch(void* const* d_in, const int* in_sizes, int n_in,
                              void* d_out, int out_size, void* d_ws, size_t ws_size,
                              hipStream_t stream) {
    const float* x    = (const float*)d_in[0];
    const float* h0   = (const float*)d_in[1];
    const float* wihT = (const float*)d_in[2];
    const float* whhT = (const float*)d_in[3];
    const float* bias = (const float*)d_in[4];
    float*       out  = (float*)d_out;

    cvt_x_kernel<<<2048, 256, 0, stream>>>(x);
    cvt_wih_kernel<<<NG, 256, 0, stream>>>(wihT);
    gi_gemm_kernel<<<1024 * 6, 256, 0, stream>>>(bias);
    gru_rec_kernel<<<BB, 1024, 0, stream>>>(h0, whhT, out);
}

// Round 19
// 1661.026 us; speedup vs baseline: 1.7274x; 1.7274x over previous
//
#include <hip/hip_runtime.h>
#include <hip/hip_fp16.h>

#define TT 1024
#define BB 128
#define II 256
#define HH 256
#define NG 768   // 3*H

// Static scratch: x bf16, wih^T bf16, gi f16 (bias folded in).
__device__ __align__(16) unsigned short g_xbf[(size_t)TT * BB * II];   // 67 MB
__device__ __align__(16) unsigned short g_wihB[NG * II];               // 384 KB
__device__ __align__(16) _Float16       g_gi[(size_t)TT * BB * NG];    // 201 MB

typedef __attribute__((ext_vector_type(8))) short    bfrag;
typedef __attribute__((ext_vector_type(8))) _Float16 hfrag;
typedef __attribute__((ext_vector_type(4))) float    f32x4;
typedef __attribute__((ext_vector_type(2))) _Float16 h2t;

__device__ __forceinline__ unsigned short f2bf(float f) {
    unsigned u = __float_as_uint(f);
    return (unsigned short)((u + 0x7fffu + ((u >> 16) & 1u)) >> 16);   // RNE
}
__device__ __forceinline__ unsigned pk2(float a, float b) {
    return __builtin_bit_cast(unsigned, __builtin_amdgcn_cvt_pkrtz(a, b));
}

// ---------------- phase 1a: x f32 -> bf16 ----------------
__global__ void cvt_x_kernel(const float* __restrict__ x) {
    const int n4 = TT * BB * II / 4;
    for (int i = blockIdx.x * blockDim.x + threadIdx.x; i < n4;
         i += gridDim.x * blockDim.x) {
        float4 v = reinterpret_cast<const float4*>(x)[i];
        ushort4 o;
        o.x = f2bf(v.x); o.y = f2bf(v.y); o.z = f2bf(v.z); o.w = f2bf(v.w);
        reinterpret_cast<ushort4*>(g_xbf)[i] = o;
    }
}

// ---------------- phase 1b: wihT [k][n] -> wihB [n][k] bf16 ----------------
__global__ void cvt_wih_kernel(const float* __restrict__ wihT) {
    const int n = blockIdx.x;
    const int k = threadIdx.x;
    g_wihB[n * II + k] = f2bf(wihT[k * NG + n]);
}

// ---------------- phase 2: gi = x @ wihT + bias (MFMA bf16, f16 out) ----------------
__global__ void __launch_bounds__(256) gi_gemm_kernel(const float* __restrict__ bias) {
    __shared__ unsigned short Ab[128 * 32];
    __shared__ unsigned short Bb[128 * 32];
    const int tid = threadIdx.x;
    const int mt = blockIdx.x / 6, nt = blockIdx.x % 6;
    const int m0 = mt * 128, n0 = nt * 128;
    const int l = tid & 63, w = tid >> 6;
    const int wr = w >> 1, wc = w & 1;
    const int srow = tid >> 2, scol = (tid & 3) * 8;

    f32x4 acc[4][4] = {};

    for (int ks = 0; ks < 8; ++ks) {
        const int k0 = ks * 32;
        __syncthreads();
        #pragma unroll
        for (int c = 0; c < 2; ++c) {
            const int row = c * 64 + srow;
            *reinterpret_cast<uint4*>(&Ab[row * 32 + scol]) =
                *reinterpret_cast<const uint4*>(&g_xbf[(size_t)(m0 + row) * II + k0 + scol]);
            *reinterpret_cast<uint4*>(&Bb[row * 32 + scol]) =
                *reinterpret_cast<const uint4*>(&g_wihB[(n0 + row) * II + k0 + scol]);
        }
        __syncthreads();
        bfrag af[4], bf[4];
        #pragma unroll
        for (int i = 0; i < 4; ++i) {
            af[i] = *reinterpret_cast<const bfrag*>(
                        &Ab[(wr * 64 + i * 16 + (l & 15)) * 32 + (l >> 4) * 8]);
            bf[i] = *reinterpret_cast<const bfrag*>(
                        &Bb[(wc * 64 + i * 16 + (l & 15)) * 32 + (l >> 4) * 8]);
        }
        #pragma unroll
        for (int mi = 0; mi < 4; ++mi)
            #pragma unroll
            for (int ni = 0; ni < 4; ++ni)
                acc[mi][ni] = __builtin_amdgcn_mfma_f32_16x16x32_bf16(
                                  af[mi], bf[ni], acc[mi][ni], 0, 0, 0);
    }
    #pragma unroll
    for (int mi = 0; mi < 4; ++mi) {
        const int grow = m0 + wr * 64 + mi * 16 + (l >> 4) * 4;
        #pragma unroll
        for (int ni = 0; ni < 4; ++ni) {
            const int gcol = n0 + wc * 64 + ni * 16 + (l & 15);
            const float bv = bias[gcol];
            #pragma unroll
            for (int q = 0; q < 4; ++q)
                g_gi[(size_t)(grow + q) * NG + gcol] = (_Float16)(acc[mi][ni][q] + bv);
        }
    }
}

// ---------------- phase 3: recurrence, MFMA(r,z) + fdot2(n) hybrid ----------------
// The weight sweep (196608 elem/CU/step) is the floor. MFMA sweeps 32
// elem/cyc/SIMD (M=1 waste); fdot2 sweeps 64 elem/cyc/SIMD and its issue
// slots fit in the MFMA pipe's 16-cyc shadow (pipes are separate; one
// interleaved instruction stream keeps both busy). So: r,z via 32
// AGPR-pinned B-frags/wave (128 words = exactly the AGPR cap at 512thr;
// r17-proven) -> 1024 cyc/SIMD; n via fdot2 with 64 packed words/lane in
// arch VGPRs (~114 arch total <= the 128-arch law) -> ~480 cyc in shadow.
// fdot2 reuses the MFMA A-fragment registers as its h source (each lane's
// A-frags hold exactly pairs KT*16+sel*4+i): ZERO extra LDS reads. The 4
// sel-groups cover disjoint k; 2x __shfl_xor(16,32) sums them lane-local.
// One barrier/step; n-gate f32-accumulated (better than r17's MFMA path).
#define MF(A, B, C) __builtin_amdgcn_mfma_f32_16x16x32_f16((A), (B), (C), 0, 0, 0)
#define FD(HU, WU, ACC)                                                     \
    __builtin_amdgcn_fdot2(__builtin_bit_cast(h2t, (unsigned)(HU)),         \
                           __builtin_bit_cast(h2t, (unsigned)(WU)), (ACC), false)

#define LDB1(NAME, CB, KT)                                                  \
    hfrag NAME;                                                             \
    _Pragma("unroll")                                                       \
    for (int e = 0; e < 8; ++e)                                             \
        NAME[e] = (_Float16)whhT[(size_t)((KT) * 32 + g8 + e) * NG + (CB) + c]; \
    asm("" : "+a"(NAME));

#define DECL8(P, CB)                                                        \
    LDB1(P##_0, CB, 0) LDB1(P##_1, CB, 1) LDB1(P##_2, CB, 2)                \
    LDB1(P##_3, CB, 3) LDB1(P##_4, CB, 4) LDB1(P##_5, CB, 5)                \
    LDB1(P##_6, CB, 6) LDB1(P##_7, CB, 7)

// n-gate weights: pair p = KT*16 + sel*4 + i, cols cn1 (=512+16w+c), cn2 (+128)
#define NWI(KT, I)                                                          \
    const unsigned NW1_##KT##_##I =                                         \
        pk2(whhT[(size_t)(2 * ((KT) * 16 + sel4 + (I))) * NG + cn1],        \
            whhT[(size_t)(2 * ((KT) * 16 + sel4 + (I)) + 1) * NG + cn1]);   \
    const unsigned NW2_##KT##_##I =                                         \
        pk2(whhT[(size_t)(2 * ((KT) * 16 + sel4 + (I))) * NG + cn2],        \
            whhT[(size_t)(2 * ((KT) * 16 + sel4 + (I)) + 1) * NG + cn2]);
#define NW8(KT) NWI(KT, 0) NWI(KT, 1) NWI(KT, 2) NWI(KT, 3)

#define KST(KT)                                                             \
    {                                                                       \
        const hfrag A = *reinterpret_cast<const hfrag*>(hl + (KT) * 32 + g8); \
        R0 = MF(A, BR0_##KT, R0); Z0 = MF(A, BZ0_##KT, Z0);                 \
        R1 = MF(A, BR1_##KT, R1); Z1 = MF(A, BZ1_##KT, Z1);                 \
        const uint4 hp4 = __builtin_bit_cast(uint4, A);                     \
        aN1 = FD(hp4.x, NW1_##KT##_0, aN1); aN2 = FD(hp4.x, NW2_##KT##_0, aN2); \
        bN1 = FD(hp4.y, NW1_##KT##_1, bN1); bN2 = FD(hp4.y, NW2_##KT##_1, bN2); \
        aN1 = FD(hp4.z, NW1_##KT##_2, aN1); aN2 = FD(hp4.z, NW2_##KT##_2, aN2); \
        bN1 = FD(hp4.w, NW1_##KT##_3, bN1); bN2 = FD(hp4.w, NW2_##KT##_3, bN2); \
    }

__global__ void __launch_bounds__(512, 1) gru_rec_kernel(
    const float* __restrict__ h0, const float* __restrict__ whhT,
    float* __restrict__ out)
{
    __shared__ __align__(16) _Float16 hbuf[2][HH];   // 1 KB ping-pong h (f16)

    const int t    = threadIdx.x;
    const int b    = blockIdx.x;
    const int w    = t >> 6;            // wave 0..7
    const int l    = t & 63;
    const int c    = l & 15;            // col within tile
    const int sel  = l >> 4;            // 0..3 (k-chunk group)
    const int sel4 = sel * 4;
    const int g8   = sel * 8;
    const int cw   = w * 16;
    const int cn1  = 512 + cw + c;      // n-gate col 1
    const int cn2  = cn1 + 128;         // n-gate col 2
    const int j    = (sel & 1) * 128 + cw + c;   // this lane's output column

    // --- r,z B-frags (32), AGPR-pinned ---
    DECL8(BR0, cw)        DECL8(BR1, 128 + cw)
    DECL8(BZ0, 256 + cw)  DECL8(BZ1, 384 + cw)
    // --- n-gate fdot2 weights: 64 packed words, arch VGPRs (named SSA) ---
    NW8(0) NW8(1) NW8(2) NW8(3) NW8(4) NW8(5) NW8(6) NW8(7)

    // --- init h ---
    float hp = h0[b * HH + j];
    hbuf[0][j] = (_Float16)hp;          // duplicate writes: same value
    __syncthreads();

    for (int ts = 0; ts < TT; ++ts) {
        const _Float16* hl  = hbuf[ts & 1];
        _Float16*       hn_ = hbuf[(ts & 1) ^ 1];

        // gi for this step (bias pre-folded; hides under the MFMA block)
        const _Float16* gb = g_gi + ((size_t)ts * BB + b) * NG + j;
        const float gR = (float)gb[0];
        const float gZ = (float)gb[256];
        const float gN = (float)gb[512];

        f32x4 R0 = {0.f,0.f,0.f,0.f}, R1 = {0.f,0.f,0.f,0.f};
        f32x4 Z0 = {0.f,0.f,0.f,0.f}, Z1 = {0.f,0.f,0.f,0.f};
        float aN1 = 0.f, bN1 = 0.f, aN2 = 0.f, bN2 = 0.f;
        KST(0) KST(1) KST(2) KST(3) KST(4) KST(5) KST(6) KST(7)

        // n-gate: sum the 4 sel-groups' disjoint-k partials (lane groups
        // c, c+16, c+32, c+48 share cols cn1/cn2)
        float n1 = aN1 + bN1;
        n1 += __shfl_xor(n1, 16); n1 += __shfl_xor(n1, 32);
        float n2 = aN2 + bN2;
        n2 += __shfl_xor(n2, 16); n2 += __shfl_xor(n2, 32);

        // all C rows equal (duplicated A rows): reg 0 = this col's r/z
        const float sR = (sel & 1) ? R1[0] : R0[0];
        const float sZ = (sel & 1) ? Z1[0] : Z0[0];
        const float sN = (sel & 1) ? n2 : n1;

        const float r  = 1.f / (1.f + __expf(-(sR + gR)));
        const float z  = 1.f / (1.f + __expf(-(sZ + gZ)));
        const float e  = __expf(2.f * (gN + r * sN));   // tanh
        const float n  = 1.f - 2.f / (e + 1.f);
        const float hv = (1.f - z) * n + z * hp;

        hp = hv;
        hn_[j] = (_Float16)hv;          // duplicate writes: same value
        if (ts == TT - 1) out[b * HH + j] = hv;
        __syncthreads();
    }
}

extern "C" void kernel_launch(void* const* d_in, const int* in_sizes, int n_in,
                              void* d_out, int out_size, void* d_ws, size_t ws_size,
                              hipStream_t stream) {
    const float* x    = (const float*)d_in[0];
    const float* h0   = (const float*)d_in[1];
    const float* wihT = (const float*)d_in[2];
    const float* whhT = (const float*)d_in[3];
    const float* bias = (const float*)d_in[4];
    float*       out  = (float*)d_out;

    cvt_x_kernel<<<2048, 256, 0, stream>>>(x);
    cvt_wih_kernel<<<NG, 256, 0, stream>>>(wihT);
    gi_gemm_kernel<<<1024 * 6, 256, 0, stream>>>(bias);
    gru_rec_kernel<<<BB, 512, 0, stream>>>(h0, whhT, out);
}